// Round 1
// baseline (181.685 us; speedup 1.0000x reference)
//
#include <hip/hip_runtime.h>

#define B_   8
#define D_   256
#define HW_  16384
#define NC_  48     // NCLS*K
#define KO_  128    // key channels

using bf16x8 = __attribute__((ext_vector_type(8))) short;
using f32x4  = __attribute__((ext_vector_type(4))) float;

__device__ __forceinline__ unsigned short f2bf(float f) {
  unsigned int u = __float_as_uint(f);
  u += 0x7FFFu + ((u >> 16) & 1u);   // RNE
  return (unsigned short)(u >> 16);
}

// ---------------- P1: q = Wq.protos + bq ; Wk->bf16 ; map init ----------------
__global__ void p1_kernel(const float* __restrict__ protos,
                          const float* __restrict__ Wq,
                          const float* __restrict__ bq,
                          const float* __restrict__ Wk,
                          unsigned short* __restrict__ wk_bf,
                          unsigned short* __restrict__ q_bf,
                          float* __restrict__ protos_out,
                          short* __restrict__ map) {
  const int c = blockIdx.x;   // 0..47
  const int b = blockIdx.y;   // 0..7
  const int o = threadIdx.x;  // 0..127
  const int i = c >> 3, j = c & 7;
  const float* wq = Wq + ((size_t)i * KO_ + o) * D_;
  const float* pp = protos + (((size_t)b * 6 + i) * 8 + j) * D_;
  float acc = bq[i * KO_ + o];
  for (int d = 0; d < D_; d += 4) {
    float4 wv = *(const float4*)(wq + d);
    float4 pv = *(const float4*)(pp + d);
    acc += wv.x * pv.x + wv.y * pv.y + wv.z * pv.z + wv.w * pv.w;
  }
  q_bf[((size_t)b * NC_ + c) * KO_ + o] = f2bf(acc);
  protos_out[((size_t)c * B_ + b) * KO_ + o] = acc;
  const int gid = (b * NC_ + c) * KO_ + o;       // 0..49151
  if (gid < KO_ * D_) wk_bf[gid] = f2bf(Wk[gid]);
  for (int idx = gid; idx < B_ * HW_; idx += NC_ * B_ * KO_) map[idx] = (short)-1;
}

// ---------------- P2: nearest prototype per sampled pixel -> map ----------------
__global__ void p2_kernel(const float* __restrict__ feats,
                          const float* __restrict__ protos,
                          const int* __restrict__ xc,
                          const int* __restrict__ yc,
                          short* __restrict__ map) {
  const int sp = blockIdx.x;
  const int b  = blockIdx.y;
  const int lane = threadIdx.x;  // 0..63
  __shared__ float sel[D_];
  const int pix = xc[sp] * 128 + yc[sp];
  const float* fb = feats + (size_t)b * D_ * HW_ + pix;
  for (int k = 0; k < 4; ++k) {
    int d = lane + k * 64;
    sel[d] = fb[(size_t)d * HW_];
  }
  __syncthreads();
  float d2 = 3.4e38f;
  int bi = lane;
  if (lane < NC_) {
    const float* pf = protos + ((size_t)b * NC_ + lane) * D_;
    float nrm = 0.f, dot = 0.f;
    for (int d = 0; d < D_; d += 4) {
      float4 pv = *(const float4*)(pf + d);
      float4 sv = *(const float4*)(sel + d);
      nrm += pv.x * pv.x + pv.y * pv.y + pv.z * pv.z + pv.w * pv.w;
      dot += pv.x * sv.x + pv.y * sv.y + pv.z * sv.z + pv.w * sv.w;
    }
    d2 = nrm - 2.f * dot;
  }
  for (int off = 32; off > 0; off >>= 1) {
    float ov = __shfl_down(d2, off);
    int   oi = __shfl_down(bi, off);
    if (ov < d2 || (ov == d2 && oi < bi)) { d2 = ov; bi = oi; }
  }
  if (lane == 0) map[(size_t)b * HW_ + pix] = (short)bi;
}

// ---------------- M: fused replace + key GEMM + sim GEMM + softmax + outputs ----------------
// 128 threads (2 waves), 32 pixels/block. LDS: F f32 [256][32] swizzled (32KB) + keyT bf16 [32][128] swizzled (8KB).
__global__ __launch_bounds__(128, 2) void m_kernel(
    const float* __restrict__ feats, const float* __restrict__ protos,
    const unsigned short* __restrict__ wk_bf, const float* __restrict__ bk,
    const unsigned short* __restrict__ q_bf, const short* __restrict__ map,
    float* __restrict__ out_assp, float* __restrict__ out_wmax,
    float* __restrict__ out_sim, float* __restrict__ out_wmean) {
  __shared__ __align__(16) unsigned char smem[40960];
  unsigned char* keyT = smem + 32768;
  float* wm = (float*)(smem + 32768);   // alias over keyT, used after barrier

  const int tid  = threadIdx.x;   // 0..127
  const int lane = tid & 63;
  const int wid  = tid >> 6;      // 0..1
  const int g    = lane >> 4;     // 0..3
  const int lr   = lane & 15;
  const int b    = blockIdx.y;
  const int p0   = blockIdx.x * 32;

  // ---- stage F tile: f32, row = d (128B), swizzle byte ^= ((d>>3)&1)<<6 ----
  {
    const int trd = tid >> 3;    // 0..15 (d sub-row)
    const int tcd = tid & 7;     // 0..7  (4 pixels each)
    const float* fb = feats + (size_t)b * D_ * HW_ + p0;
    #pragma unroll
    for (int it = 0; it < 16; ++it) {
      int d = it * 16 + trd;
      float4 v = *(const float4*)(fb + (size_t)d * HW_ + tcd * 4);
      int off = d * 128 + ((tcd * 16) ^ (((d >> 3) & 1) << 6));
      *(float4*)(smem + off) = v;
    }
  }
  __syncthreads();

  // ---- replace sampled pixels with nearest prototype (in LDS only) ----
  if (tid < 32) {
    int c = map[(size_t)b * HW_ + p0 + tid];
    if (c >= 0) {
      const float* pf = protos + ((size_t)b * NC_ + c) * D_;
      for (int d = 0; d < D_; ++d) {
        int off = d * 128 + ((tid * 4) ^ (((d >> 3) & 1) << 6));
        *(float*)(smem + off) = pf[d];
      }
    }
  }
  __syncthreads();

  const int p = wid * 16 + lr;           // pixel column within tile (0..31)

  // ---- key GEMM: key[o][p] = Wk(128x256) x F(256x32), bf16 MFMA ----
  f32x4 kacc[8] = {};
  #pragma unroll
  for (int ks = 0; ks < 8; ++ks) {
    const int k0 = ks * 32;
    bf16x8 bfrag;
    #pragma unroll
    for (int i = 0; i < 8; ++i) {
      int d = k0 + g * 8 + i;
      int off = d * 128 + ((4 * p) ^ (((d >> 3) & 1) << 6));
      bfrag[i] = (short)f2bf(*(const float*)(smem + off));
    }
    #pragma unroll
    for (int ot = 0; ot < 8; ++ot) {
      bf16x8 afrag = *(const bf16x8*)(wk_bf + (size_t)(ot * 16 + lr) * D_ + k0 + g * 8);
      kacc[ot] = __builtin_amdgcn_mfma_f32_16x16x32_bf16(afrag, bfrag, kacc[ot], 0, 0, 0);
    }
  }

  // ---- bias + write key^T to LDS as bf16, row = p (256B), swizzle ^((p&7)<<4) ----
  #pragma unroll
  for (int ot = 0; ot < 8; ++ot) {
    float4 bkv = *(const float4*)(bk + ot * 16 + g * 4);
    unsigned long long pk =
        (unsigned long long)f2bf(kacc[ot][0] + bkv.x)
      | ((unsigned long long)f2bf(kacc[ot][1] + bkv.y) << 16)
      | ((unsigned long long)f2bf(kacc[ot][2] + bkv.z) << 32)
      | ((unsigned long long)f2bf(kacc[ot][3] + bkv.w) << 48);
    int o0 = ot * 16 + g * 4;
    int off = p * 256 + ((o0 * 2) ^ ((p & 7) << 4));
    *(unsigned long long*)(keyT + off) = pk;
  }

  // ---- sim GEMM: sim[c][p] = q(48x128) x key(128x32)  (wave-local keyT rows) ----
  f32x4 sacc[3] = {};
  #pragma unroll
  for (int ks = 0; ks < 4; ++ks) {
    int o0 = ks * 32 + g * 8;
    int off = p * 256 + ((o0 * 2) ^ ((p & 7) << 4));
    bf16x8 bfrag = *(const bf16x8*)(keyT + off);
    #pragma unroll
    for (int ct = 0; ct < 3; ++ct) {
      bf16x8 afrag = *(const bf16x8*)(q_bf + ((size_t)b * NC_ + ct * 16 + lr) * KO_ + o0);
      sacc[ct] = __builtin_amdgcn_mfma_f32_16x16x32_bf16(afrag, bfrag, sacc[ct], 0, 0, 0);
    }
  }

  // ---- softmax over c (4 lanes share a pixel: xor 16, 32) ----
  float m = -3.4e38f;
  #pragma unroll
  for (int ct = 0; ct < 3; ++ct)
    #pragma unroll
    for (int r = 0; r < 4; ++r) m = fmaxf(m, sacc[ct][r]);
  m = fmaxf(m, __shfl_xor(m, 16));
  m = fmaxf(m, __shfl_xor(m, 32));
  const float sc = 1.0f / 6.0f;   // K/C = 8/48
  float s = 0.f;
  #pragma unroll
  for (int ct = 0; ct < 3; ++ct)
    #pragma unroll
    for (int r = 0; r < 4; ++r) s += __expf((sacc[ct][r] - m) * sc);
  s += __shfl_xor(s, 16);
  s += __shfl_xor(s, 32);
  const float wmax = 1.f / s;

  // ---- write sim ----
  const size_t pixg = (size_t)p0 + p;
  #pragma unroll
  for (int ct = 0; ct < 3; ++ct)
    #pragma unroll
    for (int r = 0; r < 4; ++r) {
      int c = ct * 16 + g * 4 + r;
      out_sim[((size_t)b * NC_ + c) * HW_ + pixg] = sacc[ct][r];
    }

  __syncthreads();   // all keyT reads done before aliasing wm over it
  if (g == 0) {
    wm[p] = wmax;
    out_wmax[(size_t)b * HW_ + pixg] = wmax;
    out_wmean[(size_t)b * HW_ + pixg] = 1.f / 48.f;
  }
  __syncthreads();

  // ---- weighted output: assp = F * w_max (F already replaced) ----
  {
    const int trd = tid >> 3;
    const int tcd = tid & 7;
    float* oa = out_assp + (size_t)b * D_ * HW_ + p0;
    float4 w4 = *(const float4*)(wm + tcd * 4);
    #pragma unroll
    for (int it = 0; it < 16; ++it) {
      int d = it * 16 + trd;
      int off = d * 128 + ((tcd * 16) ^ (((d >> 3) & 1) << 6));
      float4 v = *(const float4*)(smem + off);
      v.x *= w4.x; v.y *= w4.y; v.z *= w4.z; v.w *= w4.w;
      *(float4*)(oa + (size_t)d * HW_ + tcd * 4) = v;
    }
  }
}

extern "C" void kernel_launch(void* const* d_in, const int* in_sizes, int n_in,
                              void* d_out, int out_size, void* d_ws, size_t ws_size,
                              hipStream_t stream) {
  const float* feats  = (const float*)d_in[0];
  const float* protos = (const float*)d_in[1];
  const float* Wk     = (const float*)d_in[2];
  const float* bk     = (const float*)d_in[3];
  const float* Wq     = (const float*)d_in[4];
  const float* bq     = (const float*)d_in[5];
  const int*   xc     = (const int*)d_in[6];
  const int*   yc     = (const int*)d_in[7];
  const int    P      = in_sizes[6];   // 819

  float* out       = (float*)d_out;
  float* out_assp  = out;                                  // B*D*HW
  float* out_po    = out_assp + (size_t)B_ * D_ * HW_;     // 48*B*128
  float* out_wmax  = out_po + (size_t)NC_ * B_ * KO_;      // B*HW
  float* out_sim   = out_wmax + (size_t)B_ * HW_;          // B*48*HW
  float* out_wmean = out_sim + (size_t)B_ * NC_ * HW_;     // B*HW

  unsigned char* ws = (unsigned char*)d_ws;
  unsigned short* wk_bf = (unsigned short*)ws;                   // 65536 B
  unsigned short* q_bf  = (unsigned short*)(ws + 65536);         // 98304 B
  short* map            = (short*)(ws + 65536 + 98304);          // 262144 B

  p1_kernel<<<dim3(NC_, B_), 128, 0, stream>>>(protos, Wq, bq, Wk, wk_bf, q_bf, out_po, map);
  p2_kernel<<<dim3(P, B_), 64, 0, stream>>>(feats, protos, xc, yc, map);
  m_kernel<<<dim3(HW_ / 32, B_), 128, 0, stream>>>(feats, protos, wk_bf, bk, q_bf, map,
                                                   out_assp, out_wmax, out_sim, out_wmean);
}